// Round 5
// baseline (479.437 us; speedup 1.0000x reference)
//
#include <hip/hip_runtime.h>
#include <hip/hip_bf16.h>

// MergedLinearFormer: out = softmax((x@QK)@x^T / sqrt(D)) @ x @ VO
// B=4, T=4096, D=1024. 256^2-tile BK=64 bf16 GEMM, 32x32x16 MFMA,
// 2-barrier/K-tile cross-wave-skew schedule, fused exp/div epilogues.

#define BB 4
#define TT 4096
#define DD 1024

typedef __attribute__((ext_vector_type(8))) short bf16x8;
typedef __attribute__((ext_vector_type(16))) float f32x16;

__device__ __forceinline__ void gll16(const void* g, void* l) {
  __builtin_amdgcn_global_load_lds(
      (__attribute__((address_space(1))) void*)g,
      (__attribute__((address_space(3))) void*)l, 16, 0, 0);
}

#define WAIT_VM(n) asm volatile("s_waitcnt vmcnt(" #n ")" ::: "memory")
#define WAIT_LGKM0 do { asm volatile("s_waitcnt lgkmcnt(0)" ::: "memory"); \
                        __builtin_amdgcn_sched_barrier(0); } while (0)
#define BARRIER    do { __builtin_amdgcn_s_barrier(); \
                        __builtin_amdgcn_sched_barrier(0); } while (0)

// ---- x prep: read x f32 once, write xb (row-major bf16) + xT (col-major) ---
__global__ __launch_bounds__(256) void xprep_k(const float* __restrict__ in,
                                               __hip_bfloat16* __restrict__ rm,
                                               __hip_bfloat16* __restrict__ cm,
                                               int R, int C, long bs) {
  in += (long)blockIdx.z * bs; rm += (long)blockIdx.z * bs; cm += (long)blockIdx.z * bs;
  __shared__ __hip_bfloat16 tile[64][65];
  int c0 = blockIdx.x * 64, r0 = blockIdx.y * 64;
  int tx = threadIdx.x & 63, ty = threadIdx.x >> 6;
#pragma unroll
  for (int i = 0; i < 16; ++i) {
    int r = ty + i * 4;
    __hip_bfloat16 v = __float2bfloat16(in[(long)(r0 + r) * C + c0 + tx]);
    tile[r][tx] = v;
    rm[(long)(r0 + r) * C + c0 + tx] = v;
  }
  __syncthreads();
#pragma unroll
  for (int i = 0; i < 16; ++i) {
    int c = ty + i * 4;
    cm[(long)(c0 + c) * R + r0 + tx] = tile[tx][c];
  }
}

// ------------- transpose + cast (weights): f32 [R][C] -> bf16 [C][R] --------
__global__ __launch_bounds__(256) void transpose_cast_k(const float* __restrict__ in,
                                                        __hip_bfloat16* __restrict__ out,
                                                        int R, int C) {
  __shared__ __hip_bfloat16 tile[64][65];
  int c0 = blockIdx.x * 64, r0 = blockIdx.y * 64;
  int tx = threadIdx.x & 63, ty = threadIdx.x >> 6;
#pragma unroll
  for (int i = 0; i < 16; ++i) {
    int r = ty + i * 4;
    tile[r][tx] = __float2bfloat16(in[(long)(r0 + r) * C + c0 + tx]);
  }
  __syncthreads();
#pragma unroll
  for (int i = 0; i < 16; ++i) {
    int c = ty + i * 4;
    out[(long)(c0 + c) * R + r0 + tx] = tile[tx][c];
  }
}

__global__ __launch_bounds__(256) void zero_f32_k(float* __restrict__ p, int n) {
  int i = blockIdx.x * 256 + threadIdx.x;
  if (i < n) p[i] = 0.f;
}

// ------- GEMM: C[M,N] = f(A[M,K] @ Bt[N,K]^T)  (256x256, BK=64) -------------
// 8 waves (2Mx4N), per-wave 128x64 out = 4x2 32x32x16 frags x 4 k-steps.
// LDS: ring-2 x (A 32KB + B 32KB). Per K-tile: BAR, 24 ds_read_b128, lgkm(0),
// BAR, stage t+2 (8 gll16), 32 MFMA (setprio), vmcnt(8). Cross-wave skew
// inside the 2-barrier window overlaps LDS drain with MFMA.
// Swizzle: 16B phys slot = logical ^ (row&7), both-sides (rule #21).
// EPI: 0 f32*alpha, 1 bf16*alpha, 2 bf16 exp(alpha*v)+row-sum atomics,
//      3 bf16*(1/lsum[row]).
template <typename OUT_T, int EPI>
__global__ __launch_bounds__(512, 2) void gemm256(
    const __hip_bfloat16* __restrict__ A,
    const __hip_bfloat16* __restrict__ Bt,
    OUT_T* __restrict__ C,
    int M, int N, int K, float alpha,
    long sAz, long sBz, long sCz, float* __restrict__ lsum) {
  __shared__ alignas(16) char smem[131072];
  A  += (long)blockIdx.z * sAz;
  Bt += (long)blockIdx.z * sBz;
  C  += (long)blockIdx.z * sCz;

  // bijective XCD swizzle within the z-slice (nwg % 8 == 0, gridDim.x pow2)
  const int nwg = gridDim.x * gridDim.y;
  const int lin = blockIdx.x + gridDim.x * blockIdx.y;
  const int swz = (lin & 7) * (nwg >> 3) + (lin >> 3);
  const int gxsh = __popc(gridDim.x - 1);
  const int bx = swz & (gridDim.x - 1);
  const int by = swz >> gxsh;

  const int tid  = threadIdx.x;
  const int lane = tid & 63;
  const int wid  = tid >> 6;
  const int wr   = wid >> 2;        // 0..1
  const int wc   = wid & 3;         // 0..3
  const long m0 = (long)bx * 256;
  const long n0 = (long)by * 256;
  const int NT = K >> 6;            // BK=64 K-tiles; NT even, >= 2

  // staging: thread -> row (tid>>3), phys slot (tid&7), swizzled source
  const int srow = tid >> 3;
  const int sswz = (tid & 7) ^ (srow & 7);
  const __hip_bfloat16* gA = A  + (m0 + srow) * (long)K + sswz * 8;
  const __hip_bfloat16* gB = Bt + (n0 + srow) * (long)K + sswz * 8;

#define STG_A(s, c, D) gll16(gA + (long)(c) * 64 * K + (long)(s) * 64, \
                             smem + (D) + (c) * 8192 + wid * 1024)
#define STG_B(s, c, D) gll16(gB + (long)(c) * 64 * K + (long)(s) * 64, \
                             smem + (D) + 32768 + (c) * 8192 + wid * 1024)

  // fragment addressing (32x32x16): row = base + (lane&31); per lane 16B at
  // logical k-slot (ks*2 + (lane>>5)), physical = logical ^ (row&7)
  const int h   = lane >> 5;
  const int r32 = lane & 31;
  const int r7  = r32 & 7;
  int soff[4];
#pragma unroll
  for (int ks = 0; ks < 4; ++ks) soff[ks] = (((ks * 2 + h) ^ r7) << 4);
  const int aoff = (wr * 128 + r32) * 128;          // + mi*4096 + soff[ks]
  const int boff = 32768 + (wc * 64 + r32) * 128;   // + ni*4096 + soff[ks]

  f32x16 acc[4][2];
#pragma unroll
  for (int mi = 0; mi < 4; ++mi)
#pragma unroll
    for (int ni = 0; ni < 2; ++ni)
      acc[mi][ni] = (f32x16)(0.f);

  // prologue: stage tile0 (buf0) + tile1 (buf1); drain tile0
#pragma unroll
  for (int c = 0; c < 4; ++c) STG_A(0, c, 0);
#pragma unroll
  for (int c = 0; c < 4; ++c) STG_B(0, c, 0);
#pragma unroll
  for (int c = 0; c < 4; ++c) STG_A(1, c, 65536);
#pragma unroll
  for (int c = 0; c < 4; ++c) STG_B(1, c, 65536);
  WAIT_VM(8);

  for (int t = 0; t < NT; ++t) {
    BARRIER;                                 // tile t resident for all waves
    const char* bs = smem + (t & 1) * 65536;
    bf16x8 aq[4][4], bq[2][4];
#pragma unroll
    for (int mi = 0; mi < 4; ++mi)
#pragma unroll
      for (int ks = 0; ks < 4; ++ks)
        aq[mi][ks] = *(const bf16x8*)(bs + aoff + mi * 4096 + soff[ks]);
#pragma unroll
    for (int ni = 0; ni < 2; ++ni)
#pragma unroll
      for (int ks = 0; ks < 4; ++ks)
        bq[ni][ks] = *(const bf16x8*)(bs + boff + ni * 4096 + soff[ks]);
    WAIT_LGKM0;                              // this wave's frags in regs
    BARRIER;                                 // ALL waves' reads of buf done
    if (t + 2 < NT) {                        // overwrite-safe: stage t+2
      const int D_ = (t & 1) * 65536;
      STG_B(t + 2, 0, D_); STG_B(t + 2, 1, D_);
      STG_B(t + 2, 2, D_); STG_B(t + 2, 3, D_);
      STG_A(t + 2, 0, D_); STG_A(t + 2, 1, D_);
      STG_A(t + 2, 2, D_); STG_A(t + 2, 3, D_);
    }
    __builtin_amdgcn_s_setprio(1);
#pragma unroll
    for (int ks = 0; ks < 4; ++ks)
#pragma unroll
      for (int mi = 0; mi < 4; ++mi)
#pragma unroll
        for (int ni = 0; ni < 2; ++ni)
          acc[mi][ni] = __builtin_amdgcn_mfma_f32_32x32x16_bf16(
              aq[mi][ks], bq[ni][ks], acc[mi][ni], 0, 0, 0);
    __builtin_amdgcn_s_setprio(0);
    if (t + 2 < NT)      { WAIT_VM(8); }     // t+1's 8 loads complete
    else if (t + 1 < NT) { WAIT_VM(0); }
  }

  // ---- epilogue: 32x32 C/D layout col=lane&31,
  //      row = (reg&3) + 8*(reg>>2) + 4*(lane>>5)   [verified m74/m101]
  const long colb = n0 + wc * 64 + r32;
  if constexpr (EPI == 2) {
    float* lred = (float*)smem;              // [256 rows][4 wc]
    __syncthreads();
#pragma unroll
    for (int mi = 0; mi < 4; ++mi) {
#pragma unroll
      for (int reg = 0; reg < 16; ++reg) {
        const int rloc = wr * 128 + mi * 32 + (reg & 3) + 8 * (reg >> 2) + 4 * h;
        const long row = m0 + rloc;
        float rs = 0.f;
#pragma unroll
        for (int ni = 0; ni < 2; ++ni) {
          float e = __expf(acc[mi][ni][reg] * alpha);
          C[row * (long)N + colb + ni * 32] = (OUT_T)__float2bfloat16(e);
          rs += e;
        }
        rs += __shfl_xor(rs, 1);  rs += __shfl_xor(rs, 2);
        rs += __shfl_xor(rs, 4);  rs += __shfl_xor(rs, 8);
        rs += __shfl_xor(rs, 16);
        if (r32 == 0) lred[rloc * 4 + wc] = rs;
      }
    }
    __syncthreads();
    if (tid < 256) {
      float s4 = lred[tid * 4] + lred[tid * 4 + 1] + lred[tid * 4 + 2] + lred[tid * 4 + 3];
      atomicAdd(&lsum[(long)blockIdx.z * M + m0 + tid], s4);
    }
  } else if constexpr (EPI == 3) {
    float* linv = (float*)smem;              // [256] reciprocals
    __syncthreads();
    if (tid < 256) linv[tid] = 1.0f / lsum[(long)blockIdx.z * M + m0 + tid];
    __syncthreads();
#pragma unroll
    for (int mi = 0; mi < 4; ++mi) {
#pragma unroll
      for (int reg = 0; reg < 16; ++reg) {
        const int rloc = wr * 128 + mi * 32 + (reg & 3) + 8 * (reg >> 2) + 4 * h;
        const float inv = linv[rloc];
        const long row = m0 + rloc;
#pragma unroll
        for (int ni = 0; ni < 2; ++ni)
          C[row * (long)N + colb + ni * 32] =
              (OUT_T)__float2bfloat16(acc[mi][ni][reg] * inv);
      }
    }
  } else {
#pragma unroll
    for (int mi = 0; mi < 4; ++mi)
#pragma unroll
      for (int reg = 0; reg < 16; ++reg) {
        const long row = m0 + wr * 128 + mi * 32 + (reg & 3) + 8 * (reg >> 2) + 4 * h;
#pragma unroll
        for (int ni = 0; ni < 2; ++ni) {
          float v = acc[mi][ni][reg] * alpha;
          if constexpr (EPI == 0)
            C[row * (long)N + colb + ni * 32] = v;
          else
            C[row * (long)N + colb + ni * 32] = (OUT_T)__float2bfloat16(v);
        }
      }
  }
#undef STG_A
#undef STG_B
}

// ------------------------------- launch -------------------------------------
extern "C" void kernel_launch(void* const* d_in, const int* in_sizes, int n_in,
                              void* d_out, int out_size, void* d_ws, size_t ws_size,
                              hipStream_t stream) {
  const float* x  = (const float*)d_in[0];
  const float* QK = (const float*)d_in[1];
  const float* VO = (const float*)d_in[2];
  char* ws = (char*)d_ws;

  const long MB = 1l << 20;
  __hip_bfloat16* QKT  = (__hip_bfloat16*)(ws);            //  2 MB  QK^T (dead after xqk)
  float*          lsum = (float*)(ws);                     //  64 KB [B][T], reuses QKT slot
  __hip_bfloat16* VOT  = (__hip_bfloat16*)(ws + 2 * MB);   //  2 MB  VO^T
  __hip_bfloat16* xb   = (__hip_bfloat16*)(ws + 4 * MB);   // 32 MB  x bf16; later av
  __hip_bfloat16* xT   = (__hip_bfloat16*)(ws + 36 * MB);  // 32 MB  x^T per batch
  __hip_bfloat16* attn = (__hip_bfloat16*)(ws + 68 * MB);  // 128 MB [B][T][T] = P (exp'd)
  __hip_bfloat16* xqk  = (__hip_bfloat16*)d_out;           // 32 MB of the 64 MB d_out

  const long NTOK = (long)BB * TT;
  const long bstride = (long)TT * DD;
  const long aslot = (long)TT * TT;

  // 1) prep: x -> xb + xT in one pass; weight transposes
  xprep_k<<<dim3(DD / 64, TT / 64, BB), 256, 0, stream>>>(x, xb, xT, TT, DD, bstride);
  transpose_cast_k<<<dim3(16, 16, 1), 256, 0, stream>>>(QK, QKT, DD, DD);
  transpose_cast_k<<<dim3(16, 16, 1), 256, 0, stream>>>(VO, VOT, DD, DD);

  // 2) xqk_b = xb_b @ QK -> bf16 into d_out
  gemm256<__hip_bfloat16, 1><<<dim3(TT / 256, DD / 256, BB), 512, 0, stream>>>(
      xb, QKT, xqk, TT, DD, DD, 1.0f, bstride, 0, bstride, nullptr);

  // 3) lsum = 0 (QKT slot is dead now)
  zero_f32_k<<<(int)(NTOK / 256), 256, 0, stream>>>(lsum, (int)NTOK);

  // 4) P = exp(xqk @ xb^T / 32), row sums -> lsum  (z-batched, no softmax pass)
  gemm256<__hip_bfloat16, 2><<<dim3(TT / 256, TT / 256, BB), 512, 0, stream>>>(
      xqk, xb, attn, TT, TT, DD, 0.03125f, bstride, bstride, aslot, lsum);

  // 5) av_b = (P_b @ x_b) / lsum  (z-batched, writes into xb -- x dead now)
  gemm256<__hip_bfloat16, 3><<<dim3(TT / 256, DD / 256, BB), 512, 0, stream>>>(
      attn, xT, xb, TT, DD, TT, 1.0f, aslot, bstride, bstride, lsum);

  // 6) out = av @ VO  (flat M=16384, overwrites xqk region of d_out)
  gemm256<float, 0><<<dim3((int)(NTOK / 256), DD / 256, 1), 512, 0, stream>>>(
      xb, VOT, (float*)d_out, (int)NTOK, DD, DD, 1.0f, 0, 0, 0, nullptr);
}

// Round 6
// 361.324 us; speedup vs baseline: 1.3269x; 1.3269x over previous
//
#include <hip/hip_runtime.h>
#include <hip/hip_bf16.h>

// MergedLinearFormer: out = softmax((x@QK)@x^T / sqrt(D)) @ x @ VO
// B=4, T=4096, D=1024. 256^2-tile BK=64 8-phase bf16 MFMA GEMM with fused
// exp/div epilogues. R6: 2-loads-per-phase smooth staging (vmcnt(4) ledger),
// ks-outer MFMA, bare barriers.

#define BB 4
#define TT 4096
#define DD 1024

typedef __attribute__((ext_vector_type(8))) short bf16x8;
typedef __attribute__((ext_vector_type(4))) float f32x4;

__device__ __forceinline__ void gll16(const void* g, void* l) {
  __builtin_amdgcn_global_load_lds(
      (__attribute__((address_space(1))) void*)g,
      (__attribute__((address_space(3))) void*)l, 16, 0, 0);
}

#define WAIT_VM(n) asm volatile("s_waitcnt vmcnt(" #n ")" ::: "memory")
#define WAIT_LGKM0 do { asm volatile("s_waitcnt lgkmcnt(0)" ::: "memory"); \
                        __builtin_amdgcn_sched_barrier(0); } while (0)
#define BARRIER    __builtin_amdgcn_s_barrier()

// ---- x prep: read x f32 once, write xb (row-major bf16) + xT (col-major) ---
__global__ __launch_bounds__(256) void xprep_k(const float* __restrict__ in,
                                               __hip_bfloat16* __restrict__ rm,
                                               __hip_bfloat16* __restrict__ cm,
                                               int R, int C, long bs) {
  in += (long)blockIdx.z * bs; rm += (long)blockIdx.z * bs; cm += (long)blockIdx.z * bs;
  __shared__ __hip_bfloat16 tile[64][65];
  int c0 = blockIdx.x * 64, r0 = blockIdx.y * 64;
  int tx = threadIdx.x & 63, ty = threadIdx.x >> 6;
#pragma unroll
  for (int i = 0; i < 16; ++i) {
    int r = ty + i * 4;
    __hip_bfloat16 v = __float2bfloat16(in[(long)(r0 + r) * C + c0 + tx]);
    tile[r][tx] = v;
    rm[(long)(r0 + r) * C + c0 + tx] = v;
  }
  __syncthreads();
#pragma unroll
  for (int i = 0; i < 16; ++i) {
    int c = ty + i * 4;
    cm[(long)(c0 + c) * R + r0 + tx] = tile[tx][c];
  }
}

// ------------- transpose + cast (weights): f32 [R][C] -> bf16 [C][R] --------
__global__ __launch_bounds__(256) void transpose_cast_k(const float* __restrict__ in,
                                                        __hip_bfloat16* __restrict__ out,
                                                        int R, int C) {
  __shared__ __hip_bfloat16 tile[64][65];
  int c0 = blockIdx.x * 64, r0 = blockIdx.y * 64;
  int tx = threadIdx.x & 63, ty = threadIdx.x >> 6;
#pragma unroll
  for (int i = 0; i < 16; ++i) {
    int r = ty + i * 4;
    tile[r][tx] = __float2bfloat16(in[(long)(r0 + r) * C + c0 + tx]);
  }
  __syncthreads();
#pragma unroll
  for (int i = 0; i < 16; ++i) {
    int c = ty + i * 4;
    out[(long)(c0 + c) * R + r0 + tx] = tile[tx][c];
  }
}

__global__ __launch_bounds__(256) void zero_f32_k(float* __restrict__ p, int n) {
  int i = blockIdx.x * 256 + threadIdx.x;
  if (i < n) p[i] = 0.f;
}

// ------- GEMM: C[M,N] = f(A[M,K] @ Bt[N,K]^T)  (256x256, BK=64, 8 phases) ---
// 8 waves (2Mx4N). Staging: one half-tile (2 x gll16 of 8KB) EVERY phase:
//   ph1-2: A(t+1)->buf1   ph3-4: B(t+2)->buf0   ph5-6: A(t+2)->buf0
//   ph7-8: B(t+3)->buf1
// Drains: vmcnt(4) at ph4 (buf1=t+1 resident for ph5) and ph8 (buf0=t+2 for
// next ph1). WAR: each write starts after the barrier retiring that region's
// last read. In-flight <= 12, never drained to 0 mid-loop.
// EPI: 0 f32*alpha, 1 bf16*alpha, 2 bf16 exp(alpha*v)+row-sum atomics,
//      3 bf16*(1/lsum[row]).
template <typename OUT_T, int EPI>
__global__ __launch_bounds__(512, 2) void gemm256(
    const __hip_bfloat16* __restrict__ A,
    const __hip_bfloat16* __restrict__ Bt,
    OUT_T* __restrict__ C,
    int M, int N, int K, float alpha,
    long sAz, long sBz, long sCz, float* __restrict__ lsum) {
  __shared__ alignas(16) char smem[131072];
  A  += (long)blockIdx.z * sAz;
  Bt += (long)blockIdx.z * sBz;
  C  += (long)blockIdx.z * sCz;

  // bijective XCD swizzle within the z-slice (nwg % 8 == 0, gridDim.x pow2)
  const int nwg = gridDim.x * gridDim.y;
  const int lin = blockIdx.x + gridDim.x * blockIdx.y;
  const int swz = (lin & 7) * (nwg >> 3) + (lin >> 3);
  const int gxsh = __popc(gridDim.x - 1);
  const int bx = swz & (gridDim.x - 1);
  const int by = swz >> gxsh;

  const int tid  = threadIdx.x;
  const int lane = tid & 63;
  const int wid  = tid >> 6;
  const int wr   = wid >> 2;        // 0..1
  const int wc   = wid & 3;         // 0..3
  const long m0 = (long)bx * 256;
  const long n0 = (long)by * 256;
  const int NT = K >> 6;            // BK=64 K-tiles; NT even, >= 4

  // staging: thread -> row (tid>>3), phys slot (tid&7), swizzled source
  const int srow = tid >> 3;
  const int sswz = (tid & 7) ^ (srow & 7);
  const __hip_bfloat16* gA = A  + (m0 + srow) * (long)K + sswz * 8;
  const __hip_bfloat16* gB = Bt + (n0 + srow) * (long)K + sswz * 8;

#define STG_A(s, c, D) gll16(gA + (long)(c) * 64 * K + (long)(s) * 64, \
                             smem + (D) + (c) * 8192 + wid * 1024)
#define STG_B(s, c, D) gll16(gB + (long)(c) * 64 * K + (long)(s) * 64, \
                             smem + (D) + 32768 + (c) * 8192 + wid * 1024)

  // ds_read bases (loop-invariant; offsets are mi/ni*2048 immediates)
  const int fr = lane & 15, l4 = lane >> 4, f7 = lane & 7;
  const char* a00 = smem +         (wr * 128 + fr) * 128 + ((l4    ) ^ f7) * 16;
  const char* a01 = smem +         (wr * 128 + fr) * 128 + ((4 | l4) ^ f7) * 16;
  const char* b00 = smem + 32768 + (wc * 64  + fr) * 128 + ((l4    ) ^ f7) * 16;
  const char* b01 = smem + 32768 + (wc * 64  + fr) * 128 + ((4 | l4) ^ f7) * 16;
  const char* a10 = a00 + 65536; const char* a11 = a01 + 65536;
  const char* b10 = b00 + 65536; const char* b11 = b01 + 65536;

  bf16x8 aq[4][2], bq[4][2];
#define RD_A(p0, p1, MIOFF)                                         \
  _Pragma("unroll") for (int mi_ = 0; mi_ < 4; ++mi_) {             \
    aq[mi_][0] = *(const bf16x8*)((p0) + ((MIOFF) + mi_) * 2048);   \
    aq[mi_][1] = *(const bf16x8*)((p1) + ((MIOFF) + mi_) * 2048);   \
  }
#define RD_B(p0, p1, NI0)                                           \
  _Pragma("unroll") for (int ni_ = 0; ni_ < 2; ++ni_) {             \
    bq[(NI0) + ni_][0] = *(const bf16x8*)((p0) + ((NI0) + ni_) * 2048); \
    bq[(NI0) + ni_][1] = *(const bf16x8*)((p1) + ((NI0) + ni_) * 2048); \
  }

  f32x4 acc[8][4];
#pragma unroll
  for (int mi = 0; mi < 8; ++mi)
#pragma unroll
    for (int ni = 0; ni < 4; ++ni)
      acc[mi][ni] = (f32x4){0.f, 0.f, 0.f, 0.f};

  // ks OUTER: 8 independent MFMAs between dependent acc pairs
#define MFMA16(MI0, NI0)                                                       \
  do {                                                                         \
    __builtin_amdgcn_s_setprio(1);                                             \
    _Pragma("unroll") for (int ks_ = 0; ks_ < 2; ++ks_)                        \
    _Pragma("unroll") for (int mi_ = 0; mi_ < 4; ++mi_)                        \
    _Pragma("unroll") for (int ni_ = 0; ni_ < 2; ++ni_)                        \
      acc[(MI0) + mi_][(NI0) + ni_] = __builtin_amdgcn_mfma_f32_16x16x32_bf16( \
          aq[mi_][ks_], bq[(NI0) + ni_][ks_], acc[(MI0) + mi_][(NI0) + ni_],   \
          0, 0, 0);                                                            \
    __builtin_amdgcn_s_setprio(0);                                             \
  } while (0)

  // prologue: tile0 (buf0) fully + tile1's B (buf1); certify tile0
#pragma unroll
  for (int c = 0; c < 4; ++c) STG_B(0, c, 0);
#pragma unroll
  for (int c = 0; c < 4; ++c) STG_A(0, c, 0);
#pragma unroll
  for (int c = 0; c < 4; ++c) STG_B(1, c, 65536);
  WAIT_VM(4);
  BARRIER;

  for (int t2 = 0; t2 < NT; t2 += 2) {
    const bool g = (t2 + 2 < NT);
    // ---------------- K-tile t2 (buf0) ----------------
    // ph1: reads A(mi0-3)+B(ni0-1); stage A(t2+1) half0 -> buf1
    RD_A(a00, a01, 0); RD_B(b00, b01, 0);
    STG_A(t2 + 1, 0, 65536); STG_A(t2 + 1, 1, 65536);
    asm volatile("s_waitcnt lgkmcnt(8)");
    BARRIER; WAIT_LGKM0; MFMA16(0, 0); BARRIER;
    // ph2: reads B(ni2-3); stage A(t2+1) half1
    RD_B(b00, b01, 2);
    STG_A(t2 + 1, 2, 65536); STG_A(t2 + 1, 3, 65536);
    BARRIER; WAIT_LGKM0; MFMA16(0, 2); BARRIER;
    // ph3: reads A(mi4-7); stage B(t2+2) half0 -> buf0 (B reads done @ph2 bar)
    RD_A(a00, a01, 4);
    if (g) { STG_B(t2 + 2, 0, 0); STG_B(t2 + 2, 1, 0); }
    BARRIER; WAIT_LGKM0; MFMA16(4, 2); BARRIER;
    // ph4: stage B(t2+2) half1; drain -> buf1 (tile t2+1) fully resident
    if (g) { STG_B(t2 + 2, 2, 0); STG_B(t2 + 2, 3, 0); }
    MFMA16(4, 0);
    if (g) { WAIT_VM(4); } else { WAIT_VM(0); }
    BARRIER;
    // ---------------- K-tile t2+1 (buf1) ----------------
    // ph5: stage A(t2+2) half0 -> buf0 (A reads done @ph3 bar)
    RD_A(a10, a11, 0); RD_B(b10, b11, 0);
    if (g) { STG_A(t2 + 2, 0, 0); STG_A(t2 + 2, 1, 0); }
    asm volatile("s_waitcnt lgkmcnt(8)");
    BARRIER; WAIT_LGKM0; MFMA16(0, 0); BARRIER;
    // ph6: stage A(t2+2) half1
    RD_B(b10, b11, 2);
    if (g) { STG_A(t2 + 2, 2, 0); STG_A(t2 + 2, 3, 0); }
    BARRIER; WAIT_LGKM0; MFMA16(0, 2); BARRIER;
    // ph7: stage B(t2+3) half0 -> buf1 (buf1.B reads done @ph6 bar)
    RD_A(a10, a11, 4);
    if (g) { STG_B(t2 + 3, 0, 65536); STG_B(t2 + 3, 1, 65536); }
    BARRIER; WAIT_LGKM0; MFMA16(4, 2); BARRIER;
    // ph8: stage B(t2+3) half1; drain -> buf0 (tile t2+2) fully resident
    if (g) { STG_B(t2 + 3, 2, 65536); STG_B(t2 + 3, 3, 65536); }
    MFMA16(4, 0);
    if (g) { WAIT_VM(4); }
    BARRIER;
  }

  // ---- epilogue: C/D layout col=lane&15, row=(lane>>4)*4+reg [verified m89]
  if constexpr (EPI == 2) {
    // P = exp(alpha*v) in bf16 + per-row sums -> lsum atomics
    float* lred = (float*)smem;
    __syncthreads();
    for (int i = tid; i < 1024; i += 512) lred[i] = 0.f;
    __syncthreads();
#pragma unroll
    for (int mi = 0; mi < 8; ++mi) {
#pragma unroll
      for (int r = 0; r < 4; ++r) {
        const int rloc = wr * 128 + mi * 16 + (l4 << 2) + r;
        const long row = m0 + rloc;
        float rs = 0.f;
#pragma unroll
        for (int ni = 0; ni < 4; ++ni) {
          float e = __expf(acc[mi][ni][r] * alpha);
          long col = n0 + wc * 64 + ni * 16 + fr;
          C[row * (long)N + col] = (OUT_T)__float2bfloat16(e);
          rs += e;
        }
        rs += __shfl_xor(rs, 1); rs += __shfl_xor(rs, 2);
        rs += __shfl_xor(rs, 4); rs += __shfl_xor(rs, 8);
        if (fr == 0) lred[rloc * 4 + wc] = rs;
      }
    }
    __syncthreads();
    if (tid < 256) {
      float s4 = lred[tid * 4] + lred[tid * 4 + 1] + lred[tid * 4 + 2] + lred[tid * 4 + 3];
      atomicAdd(&lsum[(long)blockIdx.z * M + m0 + tid], s4);
    }
  } else if constexpr (EPI == 3) {
#pragma unroll
    for (int mi = 0; mi < 8; ++mi) {
      const long row = m0 + wr * 128 + mi * 16 + (l4 << 2);
      float4 lv = *(const float4*)&lsum[(long)blockIdx.z * M + row];
      float inv[4] = {1.f / lv.x, 1.f / lv.y, 1.f / lv.z, 1.f / lv.w};
#pragma unroll
      for (int ni = 0; ni < 4; ++ni) {
        long col = n0 + wc * 64 + ni * 16 + fr;
#pragma unroll
        for (int r = 0; r < 4; ++r)
          C[(row + r) * (long)N + col] = (OUT_T)__float2bfloat16(acc[mi][ni][r] * inv[r]);
      }
    }
  } else {
#pragma unroll
    for (int mi = 0; mi < 8; ++mi)
#pragma unroll
      for (int ni = 0; ni < 4; ++ni)
#pragma unroll
        for (int r = 0; r < 4; ++r) {
          long row = m0 + wr * 128 + mi * 16 + (l4 << 2) + r;
          long col = n0 + wc * 64 + ni * 16 + fr;
          float v = acc[mi][ni][r] * alpha;
          if constexpr (EPI == 0)
            C[row * (long)N + col] = v;
          else
            C[row * (long)N + col] = (OUT_T)__float2bfloat16(v);
        }
  }
#undef STG_A
#undef STG_B
#undef RD_A
#undef RD_B
#undef MFMA16
}

// ------------------------------- launch -------------------------------------
extern "C" void kernel_launch(void* const* d_in, const int* in_sizes, int n_in,
                              void* d_out, int out_size, void* d_ws, size_t ws_size,
                              hipStream_t stream) {
  const float* x  = (const float*)d_in[0];
  const float* QK = (const float*)d_in[1];
  const float* VO = (const float*)d_in[2];
  char* ws = (char*)d_ws;

  const long MB = 1l << 20;
  __hip_bfloat16* QKT  = (__hip_bfloat16*)(ws);            //  2 MB  QK^T (dead after xqk)
  float*          lsum = (float*)(ws);                     //  64 KB [B][T], reuses QKT slot
  __hip_bfloat16* VOT  = (__hip_bfloat16*)(ws + 2 * MB);   //  2 MB  VO^T
  __hip_bfloat16* xb   = (__hip_bfloat16*)(ws + 4 * MB);   // 32 MB  x bf16; later av
  __hip_bfloat16* xT   = (__hip_bfloat16*)(ws + 36 * MB);  // 32 MB  x^T per batch
  __hip_bfloat16* attn = (__hip_bfloat16*)(ws + 68 * MB);  // 128 MB [B][T][T] = P (exp'd)
  __hip_bfloat16* xqk  = (__hip_bfloat16*)d_out;           // 32 MB of the 64 MB d_out

  const long NTOK = (long)BB * TT;
  const long bstride = (long)TT * DD;
  const long aslot = (long)TT * TT;

  // 1) prep: x -> xb + xT in one pass; weight transposes
  xprep_k<<<dim3(DD / 64, TT / 64, BB), 256, 0, stream>>>(x, xb, xT, TT, DD, bstride);
  transpose_cast_k<<<dim3(16, 16, 1), 256, 0, stream>>>(QK, QKT, DD, DD);
  transpose_cast_k<<<dim3(16, 16, 1), 256, 0, stream>>>(VO, VOT, DD, DD);

  // 2) xqk_b = xb_b @ QK -> bf16 into d_out
  gemm256<__hip_bfloat16, 1><<<dim3(TT / 256, DD / 256, BB), 512, 0, stream>>>(
      xb, QKT, xqk, TT, DD, DD, 1.0f, bstride, 0, bstride, nullptr);

  // 3) lsum = 0 (QKT slot is dead now)
  zero_f32_k<<<(int)(NTOK / 256), 256, 0, stream>>>(lsum, (int)NTOK);

  // 4) P = exp(xqk @ xb^T / 32), row sums -> lsum  (z-batched, no softmax pass)
  gemm256<__hip_bfloat16, 2><<<dim3(TT / 256, TT / 256, BB), 512, 0, stream>>>(
      xqk, xb, attn, TT, TT, DD, 0.03125f, bstride, bstride, aslot, lsum);

  // 5) av_b = (P_b @ x_b) / lsum  (z-batched, writes into xb -- x dead now)
  gemm256<__hip_bfloat16, 3><<<dim3(TT / 256, DD / 256, BB), 512, 0, stream>>>(
      attn, xT, xb, TT, DD, TT, 1.0f, aslot, bstride, bstride, lsum);

  // 6) out = av @ VO  (flat M=16384, overwrites xqk region of d_out)
  gemm256<float, 0><<<dim3((int)(NTOK / 256), DD / 256, 1), 512, 0, stream>>>(
      xb, VOT, (float*)d_out, (int)NTOK, DD, DD, 1.0f, 0, 0, 0, nullptr);
}

// Round 7
// 345.293 us; speedup vs baseline: 1.3885x; 1.0464x over previous
//
#include <hip/hip_runtime.h>
#include <hip/hip_bf16.h>

// MergedLinearFormer: out = softmax((x@QK)@x^T / sqrt(D)) @ x @ VO
// B=4, T=4096, D=1024. 256^2-tile BK=64 8-phase bf16 MFMA GEMM, fused exp/div
// epilogues. R7: ONE barrier per phase (pre-MFMA) -> cross-wave skew overlaps
// LDS drain with MFMA; staging redistributed with >=2-phase WAR distance;
// vmcnt(2) ledger at ph4/ph8.

#define BB 4
#define TT 4096
#define DD 1024

typedef __attribute__((ext_vector_type(8))) short bf16x8;
typedef __attribute__((ext_vector_type(4))) float f32x4;

__device__ __forceinline__ void gll16(const void* g, void* l) {
  __builtin_amdgcn_global_load_lds(
      (__attribute__((address_space(1))) void*)g,
      (__attribute__((address_space(3))) void*)l, 16, 0, 0);
}

#define WAIT_VM(n) asm volatile("s_waitcnt vmcnt(" #n ")" ::: "memory")
#define WAIT_LGKM0 do { asm volatile("s_waitcnt lgkmcnt(0)" ::: "memory"); \
                        __builtin_amdgcn_sched_barrier(0); } while (0)
#define BARRIER    __builtin_amdgcn_s_barrier()

// ---- x prep: read x f32 once, write xb (row-major bf16) + xT (col-major) ---
__global__ __launch_bounds__(256) void xprep_k(const float* __restrict__ in,
                                               __hip_bfloat16* __restrict__ rm,
                                               __hip_bfloat16* __restrict__ cm,
                                               int R, int C, long bs) {
  in += (long)blockIdx.z * bs; rm += (long)blockIdx.z * bs; cm += (long)blockIdx.z * bs;
  __shared__ __hip_bfloat16 tile[64][65];
  int c0 = blockIdx.x * 64, r0 = blockIdx.y * 64;
  int tx = threadIdx.x & 63, ty = threadIdx.x >> 6;
#pragma unroll
  for (int i = 0; i < 16; ++i) {
    int r = ty + i * 4;
    __hip_bfloat16 v = __float2bfloat16(in[(long)(r0 + r) * C + c0 + tx]);
    tile[r][tx] = v;
    rm[(long)(r0 + r) * C + c0 + tx] = v;
  }
  __syncthreads();
#pragma unroll
  for (int i = 0; i < 16; ++i) {
    int c = ty + i * 4;
    cm[(long)(c0 + c) * R + r0 + tx] = tile[tx][c];
  }
}

// ------------- transpose + cast (weights): f32 [R][C] -> bf16 [C][R] --------
__global__ __launch_bounds__(256) void transpose_cast_k(const float* __restrict__ in,
                                                        __hip_bfloat16* __restrict__ out,
                                                        int R, int C) {
  __shared__ __hip_bfloat16 tile[64][65];
  int c0 = blockIdx.x * 64, r0 = blockIdx.y * 64;
  int tx = threadIdx.x & 63, ty = threadIdx.x >> 6;
#pragma unroll
  for (int i = 0; i < 16; ++i) {
    int r = ty + i * 4;
    tile[r][tx] = __float2bfloat16(in[(long)(r0 + r) * C + c0 + tx]);
  }
  __syncthreads();
#pragma unroll
  for (int i = 0; i < 16; ++i) {
    int c = ty + i * 4;
    out[(long)(c0 + c) * R + r0 + tx] = tile[tx][c];
  }
}

__global__ __launch_bounds__(256) void zero_f32_k(float* __restrict__ p, int n) {
  int i = blockIdx.x * 256 + threadIdx.x;
  if (i < n) p[i] = 0.f;
}

// ------- GEMM: C[M,N] = f(A[M,K] @ Bt[N,K]^T)  (256x256, BK=64, 8 phases) ---
// 8 waves (2Mx4N). One barrier per phase (pre-MFMA). Reads per phase:
// ph1/5: 12 (A03+B01), ph2/6: 4 (B23), ph3/7: 8 (A47), ph4/8: 0.
// Staging (2-4 gll16/phase), all >=2-phase WAR distance to last read:
//   ph1: B(t+1)h1 + A(t+1)h0 -> buf1     ph2: A(t+1)h1 -> buf1
//   ph4: B(t+2)h0 -> buf0                ph5: B(t+2)h1 + A(t+2)h0 -> buf0
//   ph6: A(t+2)h1 -> buf0                ph8: B(t+3)h0 -> buf1
// vmcnt(2) at ph4 (tile t+1 resident) and ph8 (tile t+2 resident);
// final iteration: vmcnt(0) at ph4 (the 2-allowance would strand A h1).
// EPI: 0 f32*alpha, 1 bf16*alpha, 2 bf16 exp(alpha*v)+row-sum atomics,
//      3 bf16*(1/lsum[row]).
template <typename OUT_T, int EPI>
__global__ __launch_bounds__(512, 2) void gemm256(
    const __hip_bfloat16* __restrict__ A,
    const __hip_bfloat16* __restrict__ Bt,
    OUT_T* __restrict__ C,
    int M, int N, int K, float alpha,
    long sAz, long sBz, long sCz, float* __restrict__ lsum) {
  __shared__ alignas(16) char smem[131072];
  A  += (long)blockIdx.z * sAz;
  Bt += (long)blockIdx.z * sBz;
  C  += (long)blockIdx.z * sCz;

  // bijective XCD swizzle within the z-slice (nwg % 8 == 0, gridDim.x pow2)
  const int nwg = gridDim.x * gridDim.y;
  const int lin = blockIdx.x + gridDim.x * blockIdx.y;
  const int swz = (lin & 7) * (nwg >> 3) + (lin >> 3);
  const int gxsh = __popc(gridDim.x - 1);
  const int bx = swz & (gridDim.x - 1);
  const int by = swz >> gxsh;

  const int tid  = threadIdx.x;
  const int lane = tid & 63;
  const int wid  = tid >> 6;
  const int wr   = wid >> 2;        // 0..1
  const int wc   = wid & 3;         // 0..3
  const long m0 = (long)bx * 256;
  const long n0 = (long)by * 256;
  const int NT = K >> 6;            // BK=64 K-tiles; NT even, >= 4

  // staging: thread -> row (tid>>3), phys slot (tid&7), swizzled source
  const int srow = tid >> 3;
  const int sswz = (tid & 7) ^ (srow & 7);
  const __hip_bfloat16* gA = A  + (m0 + srow) * (long)K + sswz * 8;
  const __hip_bfloat16* gB = Bt + (n0 + srow) * (long)K + sswz * 8;

#define STG_A(s, c, D) gll16(gA + (long)(c) * 64 * K + (long)(s) * 64, \
                             smem + (D) + (c) * 8192 + wid * 1024)
#define STG_B(s, c, D) gll16(gB + (long)(c) * 64 * K + (long)(s) * 64, \
                             smem + (D) + 32768 + (c) * 8192 + wid * 1024)

  // ds_read bases (loop-invariant; offsets are mi/ni*2048 immediates)
  const int fr = lane & 15, l4 = lane >> 4, f7 = lane & 7;
  const char* a00 = smem +         (wr * 128 + fr) * 128 + ((l4    ) ^ f7) * 16;
  const char* a01 = smem +         (wr * 128 + fr) * 128 + ((4 | l4) ^ f7) * 16;
  const char* b00 = smem + 32768 + (wc * 64  + fr) * 128 + ((l4    ) ^ f7) * 16;
  const char* b01 = smem + 32768 + (wc * 64  + fr) * 128 + ((4 | l4) ^ f7) * 16;
  const char* a10 = a00 + 65536; const char* a11 = a01 + 65536;
  const char* b10 = b00 + 65536; const char* b11 = b01 + 65536;

  bf16x8 aq[4][2], bq[4][2];
#define RD_A(p0, p1, MIOFF)                                         \
  _Pragma("unroll") for (int mi_ = 0; mi_ < 4; ++mi_) {             \
    aq[mi_][0] = *(const bf16x8*)((p0) + ((MIOFF) + mi_) * 2048);   \
    aq[mi_][1] = *(const bf16x8*)((p1) + ((MIOFF) + mi_) * 2048);   \
  }
#define RD_B(p0, p1, NI0)                                           \
  _Pragma("unroll") for (int ni_ = 0; ni_ < 2; ++ni_) {             \
    bq[(NI0) + ni_][0] = *(const bf16x8*)((p0) + ((NI0) + ni_) * 2048); \
    bq[(NI0) + ni_][1] = *(const bf16x8*)((p1) + ((NI0) + ni_) * 2048); \
  }

  f32x4 acc[8][4];
#pragma unroll
  for (int mi = 0; mi < 8; ++mi)
#pragma unroll
    for (int ni = 0; ni < 4; ++ni)
      acc[mi][ni] = (f32x4){0.f, 0.f, 0.f, 0.f};

  // ks OUTER: 8 independent MFMAs between dependent acc pairs
#define MFMA16(MI0, NI0)                                                       \
  do {                                                                         \
    __builtin_amdgcn_s_setprio(1);                                             \
    _Pragma("unroll") for (int ks_ = 0; ks_ < 2; ++ks_)                        \
    _Pragma("unroll") for (int mi_ = 0; mi_ < 4; ++mi_)                        \
    _Pragma("unroll") for (int ni_ = 0; ni_ < 2; ++ni_)                        \
      acc[(MI0) + mi_][(NI0) + ni_] = __builtin_amdgcn_mfma_f32_16x16x32_bf16( \
          aq[mi_][ks_], bq[(NI0) + ni_][ks_], acc[(MI0) + mi_][(NI0) + ni_],   \
          0, 0, 0);                                                            \
    __builtin_amdgcn_s_setprio(0);                                             \
  } while (0)

  // prologue: tile0 fully + B(1)h0 -> buf1; certify tile0 (allow B(1)h0 pend)
#pragma unroll
  for (int c = 0; c < 4; ++c) STG_A(0, c, 0);
#pragma unroll
  for (int c = 0; c < 4; ++c) STG_B(0, c, 0);
  STG_B(1, 0, 65536); STG_B(1, 1, 65536);
  WAIT_VM(2);
  BARRIER;

  for (int t2 = 0; t2 < NT; t2 += 2) {
    const bool g = (t2 + 2 < NT);
    // ---- ph1 (tile t2, buf0): stage B(t+1)h1 + A(t+1)h0 -> buf1
    RD_A(a00, a01, 0); RD_B(b00, b01, 0);
    STG_B(t2 + 1, 2, 65536); STG_B(t2 + 1, 3, 65536);
    STG_A(t2 + 1, 0, 65536); STG_A(t2 + 1, 1, 65536);
    asm volatile("s_waitcnt lgkmcnt(8)");
    BARRIER; WAIT_LGKM0; MFMA16(0, 0);
    // ---- ph2: stage A(t+1)h1 -> buf1
    RD_B(b00, b01, 2);
    STG_A(t2 + 1, 2, 65536); STG_A(t2 + 1, 3, 65536);
    BARRIER; WAIT_LGKM0; MFMA16(0, 2);
    // ---- ph3
    RD_A(a00, a01, 4);
    BARRIER; WAIT_LGKM0; MFMA16(4, 2);
    // ---- ph4: stage B(t+2)h0 -> buf0; certify tile t+1 resident
    if (g) { STG_B(t2 + 2, 0, 0); STG_B(t2 + 2, 1, 0); WAIT_VM(2); }
    else   { WAIT_VM(0); }
    BARRIER; MFMA16(4, 0);
    // ---- ph5 (tile t2+1, buf1): stage B(t+2)h1 + A(t+2)h0 -> buf0
    RD_A(a10, a11, 0); RD_B(b10, b11, 0);
    if (g) { STG_B(t2 + 2, 2, 0); STG_B(t2 + 2, 3, 0);
             STG_A(t2 + 2, 0, 0); STG_A(t2 + 2, 1, 0); }
    asm volatile("s_waitcnt lgkmcnt(8)");
    BARRIER; WAIT_LGKM0; MFMA16(0, 0);
    // ---- ph6: stage A(t+2)h1 -> buf0
    RD_B(b10, b11, 2);
    if (g) { STG_A(t2 + 2, 2, 0); STG_A(t2 + 2, 3, 0); }
    BARRIER; WAIT_LGKM0; MFMA16(0, 2);
    // ---- ph7
    RD_A(a10, a11, 4);
    BARRIER; WAIT_LGKM0; MFMA16(4, 2);
    // ---- ph8: stage B(t+3)h0 -> buf1; certify tile t+2 resident
    if (g) { STG_B(t2 + 3, 0, 65536); STG_B(t2 + 3, 1, 65536); WAIT_VM(2); }
    BARRIER; MFMA16(4, 0);
  }

  // ---- epilogue: C/D layout col=lane&15, row=(lane>>4)*4+reg [verified m89]
  if constexpr (EPI == 2) {
    // P = exp(alpha*v) in bf16 + per-row sums -> lsum atomics
    float* lred = (float*)smem;
    __syncthreads();
    for (int i = tid; i < 1024; i += 512) lred[i] = 0.f;
    __syncthreads();
#pragma unroll
    for (int mi = 0; mi < 8; ++mi) {
#pragma unroll
      for (int r = 0; r < 4; ++r) {
        const int rloc = wr * 128 + mi * 16 + (l4 << 2) + r;
        const long row = m0 + rloc;
        float rs = 0.f;
#pragma unroll
        for (int ni = 0; ni < 4; ++ni) {
          float e = __expf(acc[mi][ni][r] * alpha);
          long col = n0 + wc * 64 + ni * 16 + fr;
          C[row * (long)N + col] = (OUT_T)__float2bfloat16(e);
          rs += e;
        }
        rs += __shfl_xor(rs, 1); rs += __shfl_xor(rs, 2);
        rs += __shfl_xor(rs, 4); rs += __shfl_xor(rs, 8);
        if (fr == 0) lred[rloc * 4 + wc] = rs;
      }
    }
    __syncthreads();
    if (tid < 256) {
      float s4 = lred[tid * 4] + lred[tid * 4 + 1] + lred[tid * 4 + 2] + lred[tid * 4 + 3];
      atomicAdd(&lsum[(long)blockIdx.z * M + m0 + tid], s4);
    }
  } else if constexpr (EPI == 3) {
#pragma unroll
    for (int mi = 0; mi < 8; ++mi) {
      const long row = m0 + wr * 128 + mi * 16 + (l4 << 2);
      float4 lv = *(const float4*)&lsum[(long)blockIdx.z * M + row];
      float inv[4] = {1.f / lv.x, 1.f / lv.y, 1.f / lv.z, 1.f / lv.w};
#pragma unroll
      for (int ni = 0; ni < 4; ++ni) {
        long col = n0 + wc * 64 + ni * 16 + fr;
#pragma unroll
        for (int r = 0; r < 4; ++r)
          C[(row + r) * (long)N + col] = (OUT_T)__float2bfloat16(acc[mi][ni][r] * inv[r]);
      }
    }
  } else {
#pragma unroll
    for (int mi = 0; mi < 8; ++mi)
#pragma unroll
      for (int ni = 0; ni < 4; ++ni)
#pragma unroll
        for (int r = 0; r < 4; ++r) {
          long row = m0 + wr * 128 + mi * 16 + (l4 << 2) + r;
          long col = n0 + wc * 64 + ni * 16 + fr;
          float v = acc[mi][ni][r] * alpha;
          if constexpr (EPI == 0)
            C[row * (long)N + col] = v;
          else
            C[row * (long)N + col] = (OUT_T)__float2bfloat16(v);
        }
  }
#undef STG_A
#undef STG_B
#undef RD_A
#undef RD_B
#undef MFMA16
}

// ------------------------------- launch -------------------------------------
extern "C" void kernel_launch(void* const* d_in, const int* in_sizes, int n_in,
                              void* d_out, int out_size, void* d_ws, size_t ws_size,
                              hipStream_t stream) {
  const float* x  = (const float*)d_in[0];
  const float* QK = (const float*)d_in[1];
  const float* VO = (const float*)d_in[2];
  char* ws = (char*)d_ws;

  const long MB = 1l << 20;
  __hip_bfloat16* QKT  = (__hip_bfloat16*)(ws);            //  2 MB  QK^T (dead after xqk)
  float*          lsum = (float*)(ws);                     //  64 KB [B][T], reuses QKT slot
  __hip_bfloat16* VOT  = (__hip_bfloat16*)(ws + 2 * MB);   //  2 MB  VO^T
  __hip_bfloat16* xb   = (__hip_bfloat16*)(ws + 4 * MB);   // 32 MB  x bf16; later av
  __hip_bfloat16* xT   = (__hip_bfloat16*)(ws + 36 * MB);  // 32 MB  x^T per batch
  __hip_bfloat16* attn = (__hip_bfloat16*)(ws + 68 * MB);  // 128 MB [B][T][T] = P (exp'd)
  __hip_bfloat16* xqk  = (__hip_bfloat16*)d_out;           // 32 MB of the 64 MB d_out

  const long NTOK = (long)BB * TT;
  const long bstride = (long)TT * DD;
  const long aslot = (long)TT * TT;

  // 1) prep: x -> xb + xT in one pass; weight transposes
  xprep_k<<<dim3(DD / 64, TT / 64, BB), 256, 0, stream>>>(x, xb, xT, TT, DD, bstride);
  transpose_cast_k<<<dim3(16, 16, 1), 256, 0, stream>>>(QK, QKT, DD, DD);
  transpose_cast_k<<<dim3(16, 16, 1), 256, 0, stream>>>(VO, VOT, DD, DD);

  // 2) xqk_b = xb_b @ QK -> bf16 into d_out
  gemm256<__hip_bfloat16, 1><<<dim3(TT / 256, DD / 256, BB), 512, 0, stream>>>(
      xb, QKT, xqk, TT, DD, DD, 1.0f, bstride, 0, bstride, nullptr);

  // 3) lsum = 0 (QKT slot is dead now)
  zero_f32_k<<<(int)(NTOK / 256), 256, 0, stream>>>(lsum, (int)NTOK);

  // 4) P = exp(xqk @ xb^T / 32), row sums -> lsum  (z-batched, no softmax pass)
  gemm256<__hip_bfloat16, 2><<<dim3(TT / 256, TT / 256, BB), 512, 0, stream>>>(
      xqk, xb, attn, TT, TT, DD, 0.03125f, bstride, bstride, aslot, lsum);

  // 5) av_b = (P_b @ x_b) / lsum  (z-batched, writes into xb -- x dead now)
  gemm256<__hip_bfloat16, 3><<<dim3(TT / 256, DD / 256, BB), 512, 0, stream>>>(
      attn, xT, xb, TT, DD, TT, 1.0f, aslot, bstride, bstride, lsum);

  // 6) out = av @ VO  (flat M=16384, overwrites xqk region of d_out)
  gemm256<float, 0><<<dim3((int)(NTOK / 256), DD / 256, 1), 512, 0, stream>>>(
      xb, VOT, (float*)d_out, (int)NTOK, DD, DD, 1.0f, 0, 0, 0, nullptr);
}

// Round 8
// 336.143 us; speedup vs baseline: 1.4263x; 1.0272x over previous
//
#include <hip/hip_runtime.h>
#include <hip/hip_bf16.h>

// MergedLinearFormer: out = softmax((x@QK)@x^T / sqrt(D)) @ x @ VO
// B=4, T=4096, D=1024. 256^2-tile BK=64 8-phase bf16 MFMA GEMM, fused exp/div
// epilogues. R8: 2-D chunked XCD swizzle (CXxCY tile rectangles per XCD) so
// A-panel and B-panel sharers are co-resident in one XCD's L2.

#define BB 4
#define TT 4096
#define DD 1024

typedef __attribute__((ext_vector_type(8))) short bf16x8;
typedef __attribute__((ext_vector_type(4))) float f32x4;

__device__ __forceinline__ void gll16(const void* g, void* l) {
  __builtin_amdgcn_global_load_lds(
      (__attribute__((address_space(1))) void*)g,
      (__attribute__((address_space(3))) void*)l, 16, 0, 0);
}

#define WAIT_VM(n) asm volatile("s_waitcnt vmcnt(" #n ")" ::: "memory")
#define WAIT_LGKM0 do { asm volatile("s_waitcnt lgkmcnt(0)" ::: "memory"); \
                        __builtin_amdgcn_sched_barrier(0); } while (0)
#define BARRIER    __builtin_amdgcn_s_barrier()

// ---- x prep: read x f32 once, write xb (row-major bf16) + xT (col-major) ---
__global__ __launch_bounds__(256) void xprep_k(const float* __restrict__ in,
                                               __hip_bfloat16* __restrict__ rm,
                                               __hip_bfloat16* __restrict__ cm,
                                               int R, int C, long bs) {
  in += (long)blockIdx.z * bs; rm += (long)blockIdx.z * bs; cm += (long)blockIdx.z * bs;
  __shared__ __hip_bfloat16 tile[64][65];
  int c0 = blockIdx.x * 64, r0 = blockIdx.y * 64;
  int tx = threadIdx.x & 63, ty = threadIdx.x >> 6;
#pragma unroll
  for (int i = 0; i < 16; ++i) {
    int r = ty + i * 4;
    __hip_bfloat16 v = __float2bfloat16(in[(long)(r0 + r) * C + c0 + tx]);
    tile[r][tx] = v;
    rm[(long)(r0 + r) * C + c0 + tx] = v;
  }
  __syncthreads();
#pragma unroll
  for (int i = 0; i < 16; ++i) {
    int c = ty + i * 4;
    cm[(long)(c0 + c) * R + r0 + tx] = tile[tx][c];
  }
}

// ------------- transpose + cast (weights): f32 [R][C] -> bf16 [C][R] --------
__global__ __launch_bounds__(256) void transpose_cast_k(const float* __restrict__ in,
                                                        __hip_bfloat16* __restrict__ out,
                                                        int R, int C) {
  __shared__ __hip_bfloat16 tile[64][65];
  int c0 = blockIdx.x * 64, r0 = blockIdx.y * 64;
  int tx = threadIdx.x & 63, ty = threadIdx.x >> 6;
#pragma unroll
  for (int i = 0; i < 16; ++i) {
    int r = ty + i * 4;
    tile[r][tx] = __float2bfloat16(in[(long)(r0 + r) * C + c0 + tx]);
  }
  __syncthreads();
#pragma unroll
  for (int i = 0; i < 16; ++i) {
    int c = ty + i * 4;
    out[(long)(c0 + c) * R + r0 + tx] = tile[tx][c];
  }
}

__global__ __launch_bounds__(256) void zero_f32_k(float* __restrict__ p, int n) {
  int i = blockIdx.x * 256 + threadIdx.x;
  if (i < n) p[i] = 0.f;
}

// ------- GEMM: C[M,N] = f(A[M,K] @ Bt[N,K]^T)  (256x256, BK=64, 8 phases) ---
// 8 waves (2Mx4N). One barrier per phase (pre-MFMA); staging with >=2-phase
// WAR distance; vmcnt(2) at ph4/ph8 (R7-verified schedule, unchanged).
// R8: chunked XCD swizzle -- each XCD gets a cx*cy rectangle of tiles.
// EPI: 0 f32*alpha, 1 bf16*alpha, 2 bf16 exp(alpha*v)+row-sum atomics,
//      3 bf16*(1/lsum[row]).
template <typename OUT_T, int EPI>
__global__ __launch_bounds__(512, 2) void gemm256(
    const __hip_bfloat16* __restrict__ A,
    const __hip_bfloat16* __restrict__ Bt,
    OUT_T* __restrict__ C,
    int M, int N, int K, float alpha,
    long sAz, long sBz, long sCz, float* __restrict__ lsum,
    int cx, int cy) {
  __shared__ alignas(16) char smem[131072];
  A  += (long)blockIdx.z * sAz;
  Bt += (long)blockIdx.z * sBz;
  C  += (long)blockIdx.z * sCz;

  // chunked XCD swizzle: hw lin -> xcd = lin&7; XCD processes cx*cy tile
  // rectangles. Requires nwg%8==0, GX%cx==0, GY%cy==0, (nwg/8)%(cx*cy)==0.
  const int lin = blockIdx.x + gridDim.x * blockIdx.y;
  const int xcd = lin & 7;
  const int s   = lin >> 3;
  const int rpc = cx * cy;
  const int r   = xcd + 8 * (s / rpc);
  const int p   = s % rpc;
  const int rx  = gridDim.x / cx;
  const int bx  = (r % rx) * cx + p % cx;
  const int by  = (r / rx) * cy + p / cx;

  const int tid  = threadIdx.x;
  const int lane = tid & 63;
  const int wid  = tid >> 6;
  const int wr   = wid >> 2;        // 0..1
  const int wc   = wid & 3;         // 0..3
  const long m0 = (long)bx * 256;
  const long n0 = (long)by * 256;
  const int NT = K >> 6;            // BK=64 K-tiles; NT even, >= 4

  // staging: thread -> row (tid>>3), phys slot (tid&7), swizzled source
  const int srow = tid >> 3;
  const int sswz = (tid & 7) ^ (srow & 7);
  const __hip_bfloat16* gA = A  + (m0 + srow) * (long)K + sswz * 8;
  const __hip_bfloat16* gB = Bt + (n0 + srow) * (long)K + sswz * 8;

#define STG_A(s_, c_, D_) gll16(gA + (long)(c_) * 64 * K + (long)(s_) * 64, \
                                smem + (D_) + (c_) * 8192 + wid * 1024)
#define STG_B(s_, c_, D_) gll16(gB + (long)(c_) * 64 * K + (long)(s_) * 64, \
                                smem + (D_) + 32768 + (c_) * 8192 + wid * 1024)

  // ds_read bases (loop-invariant; offsets are mi/ni*2048 immediates)
  const int fr = lane & 15, l4 = lane >> 4, f7 = lane & 7;
  const char* a00 = smem +         (wr * 128 + fr) * 128 + ((l4    ) ^ f7) * 16;
  const char* a01 = smem +         (wr * 128 + fr) * 128 + ((4 | l4) ^ f7) * 16;
  const char* b00 = smem + 32768 + (wc * 64  + fr) * 128 + ((l4    ) ^ f7) * 16;
  const char* b01 = smem + 32768 + (wc * 64  + fr) * 128 + ((4 | l4) ^ f7) * 16;
  const char* a10 = a00 + 65536; const char* a11 = a01 + 65536;
  const char* b10 = b00 + 65536; const char* b11 = b01 + 65536;

  bf16x8 aq[4][2], bq[4][2];
#define RD_A(p0, p1, MIOFF)                                         \
  _Pragma("unroll") for (int mi_ = 0; mi_ < 4; ++mi_) {             \
    aq[mi_][0] = *(const bf16x8*)((p0) + ((MIOFF) + mi_) * 2048);   \
    aq[mi_][1] = *(const bf16x8*)((p1) + ((MIOFF) + mi_) * 2048);   \
  }
#define RD_B(p0, p1, NI0)                                           \
  _Pragma("unroll") for (int ni_ = 0; ni_ < 2; ++ni_) {             \
    bq[(NI0) + ni_][0] = *(const bf16x8*)((p0) + ((NI0) + ni_) * 2048); \
    bq[(NI0) + ni_][1] = *(const bf16x8*)((p1) + ((NI0) + ni_) * 2048); \
  }

  f32x4 acc[8][4];
#pragma unroll
  for (int mi = 0; mi < 8; ++mi)
#pragma unroll
    for (int ni = 0; ni < 4; ++ni)
      acc[mi][ni] = (f32x4){0.f, 0.f, 0.f, 0.f};

  // ks OUTER: 8 independent MFMAs between dependent acc pairs
#define MFMA16(MI0, NI0)                                                       \
  do {                                                                         \
    __builtin_amdgcn_s_setprio(1);                                             \
    _Pragma("unroll") for (int ks_ = 0; ks_ < 2; ++ks_)                        \
    _Pragma("unroll") for (int mi_ = 0; mi_ < 4; ++mi_)                        \
    _Pragma("unroll") for (int ni_ = 0; ni_ < 2; ++ni_)                        \
      acc[(MI0) + mi_][(NI0) + ni_] = __builtin_amdgcn_mfma_f32_16x16x32_bf16( \
          aq[mi_][ks_], bq[(NI0) + ni_][ks_], acc[(MI0) + mi_][(NI0) + ni_],   \
          0, 0, 0);                                                            \
    __builtin_amdgcn_s_setprio(0);                                             \
  } while (0)

  // prologue: tile0 fully + B(1)h0 -> buf1; certify tile0 (allow B(1)h0 pend)
#pragma unroll
  for (int c = 0; c < 4; ++c) STG_A(0, c, 0);
#pragma unroll
  for (int c = 0; c < 4; ++c) STG_B(0, c, 0);
  STG_B(1, 0, 65536); STG_B(1, 1, 65536);
  WAIT_VM(2);
  BARRIER;

  for (int t2 = 0; t2 < NT; t2 += 2) {
    const bool g = (t2 + 2 < NT);
    // ---- ph1 (tile t2, buf0): stage B(t+1)h1 + A(t+1)h0 -> buf1
    RD_A(a00, a01, 0); RD_B(b00, b01, 0);
    STG_B(t2 + 1, 2, 65536); STG_B(t2 + 1, 3, 65536);
    STG_A(t2 + 1, 0, 65536); STG_A(t2 + 1, 1, 65536);
    asm volatile("s_waitcnt lgkmcnt(8)");
    BARRIER; WAIT_LGKM0; MFMA16(0, 0);
    // ---- ph2: stage A(t+1)h1 -> buf1
    RD_B(b00, b01, 2);
    STG_A(t2 + 1, 2, 65536); STG_A(t2 + 1, 3, 65536);
    BARRIER; WAIT_LGKM0; MFMA16(0, 2);
    // ---- ph3
    RD_A(a00, a01, 4);
    BARRIER; WAIT_LGKM0; MFMA16(4, 2);
    // ---- ph4: stage B(t+2)h0 -> buf0; certify tile t+1 resident
    if (g) { STG_B(t2 + 2, 0, 0); STG_B(t2 + 2, 1, 0); WAIT_VM(2); }
    else   { WAIT_VM(0); }
    BARRIER; MFMA16(4, 0);
    // ---- ph5 (tile t2+1, buf1): stage B(t+2)h1 + A(t+2)h0 -> buf0
    RD_A(a10, a11, 0); RD_B(b10, b11, 0);
    if (g) { STG_B(t2 + 2, 2, 0); STG_B(t2 + 2, 3, 0);
             STG_A(t2 + 2, 0, 0); STG_A(t2 + 2, 1, 0); }
    asm volatile("s_waitcnt lgkmcnt(8)");
    BARRIER; WAIT_LGKM0; MFMA16(0, 0);
    // ---- ph6: stage A(t+2)h1 -> buf0
    RD_B(b10, b11, 2);
    if (g) { STG_A(t2 + 2, 2, 0); STG_A(t2 + 2, 3, 0); }
    BARRIER; WAIT_LGKM0; MFMA16(0, 2);
    // ---- ph7
    RD_A(a10, a11, 4);
    BARRIER; WAIT_LGKM0; MFMA16(4, 2);
    // ---- ph8: stage B(t+3)h0 -> buf1; certify tile t+2 resident
    if (g) { STG_B(t2 + 3, 0, 65536); STG_B(t2 + 3, 1, 65536); WAIT_VM(2); }
    BARRIER; MFMA16(4, 0);
  }

  // ---- epilogue: C/D layout col=lane&15, row=(lane>>4)*4+reg [verified m89]
  if constexpr (EPI == 2) {
    // P = exp(alpha*v) in bf16 + per-row sums -> lsum atomics
    float* lred = (float*)smem;
    __syncthreads();
    for (int i = tid; i < 1024; i += 512) lred[i] = 0.f;
    __syncthreads();
#pragma unroll
    for (int mi = 0; mi < 8; ++mi) {
#pragma unroll
      for (int r_ = 0; r_ < 4; ++r_) {
        const int rloc = wr * 128 + mi * 16 + (l4 << 2) + r_;
        const long row = m0 + rloc;
        float rs = 0.f;
#pragma unroll
        for (int ni = 0; ni < 4; ++ni) {
          float e = __expf(acc[mi][ni][r_] * alpha);
          long col = n0 + wc * 64 + ni * 16 + fr;
          C[row * (long)N + col] = (OUT_T)__float2bfloat16(e);
          rs += e;
        }
        rs += __shfl_xor(rs, 1); rs += __shfl_xor(rs, 2);
        rs += __shfl_xor(rs, 4); rs += __shfl_xor(rs, 8);
        if (fr == 0) lred[rloc * 4 + wc] = rs;
      }
    }
    __syncthreads();
    if (tid < 256) {
      float s4 = lred[tid * 4] + lred[tid * 4 + 1] + lred[tid * 4 + 2] + lred[tid * 4 + 3];
      atomicAdd(&lsum[(long)blockIdx.z * M + m0 + tid], s4);
    }
  } else if constexpr (EPI == 3) {
#pragma unroll
    for (int mi = 0; mi < 8; ++mi) {
      const long row = m0 + wr * 128 + mi * 16 + (l4 << 2);
      float4 lv = *(const float4*)&lsum[(long)blockIdx.z * M + row];
      float inv[4] = {1.f / lv.x, 1.f / lv.y, 1.f / lv.z, 1.f / lv.w};
#pragma unroll
      for (int ni = 0; ni < 4; ++ni) {
        long col = n0 + wc * 64 + ni * 16 + fr;
#pragma unroll
        for (int r_ = 0; r_ < 4; ++r_)
          C[(row + r_) * (long)N + col] = (OUT_T)__float2bfloat16(acc[mi][ni][r_] * inv[r_]);
      }
    }
  } else {
#pragma unroll
    for (int mi = 0; mi < 8; ++mi)
#pragma unroll
      for (int ni = 0; ni < 4; ++ni)
#pragma unroll
        for (int r_ = 0; r_ < 4; ++r_) {
          long row = m0 + wr * 128 + mi * 16 + (l4 << 2) + r_;
          long col = n0 + wc * 64 + ni * 16 + fr;
          float v = acc[mi][ni][r_] * alpha;
          if constexpr (EPI == 0)
            C[row * (long)N + col] = v;
          else
            C[row * (long)N + col] = (OUT_T)__float2bfloat16(v);
        }
  }
#undef STG_A
#undef STG_B
#undef RD_A
#undef RD_B
#undef MFMA16
}

// ------------------------------- launch -------------------------------------
extern "C" void kernel_launch(void* const* d_in, const int* in_sizes, int n_in,
                              void* d_out, int out_size, void* d_ws, size_t ws_size,
                              hipStream_t stream) {
  const float* x  = (const float*)d_in[0];
  const float* QK = (const float*)d_in[1];
  const float* VO = (const float*)d_in[2];
  char* ws = (char*)d_ws;

  const long MB = 1l << 20;
  __hip_bfloat16* QKT  = (__hip_bfloat16*)(ws);            //  2 MB  QK^T (dead after xqk)
  float*          lsum = (float*)(ws);                     //  64 KB [B][T], reuses QKT slot
  __hip_bfloat16* VOT  = (__hip_bfloat16*)(ws + 2 * MB);   //  2 MB  VO^T
  __hip_bfloat16* xb   = (__hip_bfloat16*)(ws + 4 * MB);   // 32 MB  x bf16; later av
  __hip_bfloat16* xT   = (__hip_bfloat16*)(ws + 36 * MB);  // 32 MB  x^T per batch
  __hip_bfloat16* attn = (__hip_bfloat16*)(ws + 68 * MB);  // 128 MB [B][T][T] = P (exp'd)
  __hip_bfloat16* xqk  = (__hip_bfloat16*)d_out;           // 32 MB of the 64 MB d_out

  const long NTOK = (long)BB * TT;
  const long bstride = (long)TT * DD;
  const long aslot = (long)TT * TT;

  // 1) prep: x -> xb + xT in one pass; weight transposes
  xprep_k<<<dim3(DD / 64, TT / 64, BB), 256, 0, stream>>>(x, xb, xT, TT, DD, bstride);
  transpose_cast_k<<<dim3(16, 16, 1), 256, 0, stream>>>(QK, QKT, DD, DD);
  transpose_cast_k<<<dim3(16, 16, 1), 256, 0, stream>>>(VO, VOT, DD, DD);

  // 2) xqk_b = xb_b @ QK -> bf16 into d_out   (chunk 2x4: A-reuse in-XCD)
  gemm256<__hip_bfloat16, 1><<<dim3(TT / 256, DD / 256, BB), 512, 0, stream>>>(
      xb, QKT, xqk, TT, DD, DD, 1.0f, bstride, 0, bstride, nullptr, 2, 4);

  // 3) lsum = 0 (QKT slot is dead now)
  zero_f32_k<<<(int)(NTOK / 256), 256, 0, stream>>>(lsum, (int)NTOK);

  // 4) P = exp(xqk @ xb^T / 32), row sums -> lsum  (chunk 4x8 per XCD)
  gemm256<__hip_bfloat16, 2><<<dim3(TT / 256, TT / 256, BB), 512, 0, stream>>>(
      xqk, xb, attn, TT, TT, DD, 0.03125f, bstride, bstride, aslot, lsum, 4, 8);

  // 5) av_b = (P_b @ x_b) / lsum  (chunk 2x4: P-panel sharers co-XCD)
  gemm256<__hip_bfloat16, 3><<<dim3(TT / 256, DD / 256, BB), 512, 0, stream>>>(
      attn, xT, xb, TT, DD, TT, 1.0f, aslot, bstride, bstride, lsum, 2, 4);

  // 6) out = av @ VO  (chunk 8x4)
  gemm256<float, 0><<<dim3((int)(NTOK / 256), DD / 256, 1), 512, 0, stream>>>(
      xb, VOT, (float*)d_out, (int)NTOK, DD, DD, 1.0f, 0, 0, 0, nullptr, 8, 4);
}